// Round 17
// baseline (130.906 us; speedup 1.0000x reference)
//
#include <hip/hip_runtime.h>

// PerceptronSP: 8000 independent per-pixel MLPs sharing input x.
//   h1 = leaky(x @ W1[p] + b1[p])   [32x25]@[25x128]   f32 VALU
//   h2 = leaky(h1 @ W2[p] + b2[p])  [32x128]@[128x128] bf16 MFMA
//   y[:,p] = h2 @ W3[p] + b3[p]
// ~650 MB streamed once -> ~100 us floor @ 6.6 TB/s.
//
// R14 (4th submit; repeated transport-level infra failures on the same
// container, kernel never ran): mfma_f32_32x32x16_bf16 (K=16) -> one
// [16k x 64n] 4KB tile = one K-step. Double buffer 2x4KB, LDS 19.2 KB -> 8
// blocks/CU AND 256B staging segments (R13 had 128B). B-frag ds_read_b32
// conflict-free (bank = lane&31); h1 tile XOR-swizzled (byte ^= (row&7)<<4)
// for A-frag b128 reads. A/B share k-mapping (k = 8*(lane>>5)+j) -> HW
// K-permutation cancels (verified R8/R12/R13). C/D: col=lane&31,
// row=(reg&3)+8*(reg>>2)+4*(lane>>5) (guide m74/m101). Pipeline: vmcnt(4) ->
// consume -> lgkmcnt(0) -> restage, 2 tiles in flight, drain only at tail.

constexpr int DIM_IN = 25;
constexpr int H      = 128;
constexpr int P      = 8000;
constexpr int BS     = 32;
constexpr float NEG  = 0.01f;

typedef short  short4v __attribute__((ext_vector_type(4)));
typedef short  short8v __attribute__((ext_vector_type(8)));
typedef float  f32x16  __attribute__((ext_vector_type(16)));

__device__ __forceinline__ float leaky(float v) { return v >= 0.f ? v : NEG * v; }

__device__ __forceinline__ short bf_rne(float f) {   // f32 -> bf16 bits, RNE
    unsigned u = __builtin_bit_cast(unsigned, f);
    return (short)((u + 0x7fffu + ((u >> 16) & 1u)) >> 16);
}
__device__ __forceinline__ short bf_rna(float f) {   // f32 -> bf16 bits, round-nearest-away
    unsigned u = __builtin_bit_cast(unsigned, f);
    return (short)((u + 0x8000u) >> 16);
}

// stage one 4KB tile: W2 rows [16*KT,+16) x cols [64*HF,+64).
// 4 insts x 1KB; inst i covers rows 4i..4i+3, each row 256B contiguous.
// LDS linear -> buf is [16][64] f32 row-major.
#define STAGE_T(BUF, KT, HF) {                                                 \
    const float* gsrc_ = W2p + (size_t)(16 * (KT) + (t >> 4)) * H              \
                         + 64 * (HF) + ((t & 15) << 2);                        \
    float* dst_ = &w2t[BUF][0];                                                \
    _Pragma("unroll")                                                          \
    for (int i_ = 0; i_ < 4; ++i_)                                             \
        __builtin_amdgcn_global_load_lds(                                      \
            (const __attribute__((address_space(1))) unsigned*)(gsrc_ + (size_t)i_ * 4 * H), \
            (__attribute__((address_space(3))) unsigned*)(dst_ + i_ * 256),    \
            16, 0, 0); }

// consume one tile = one K=16 step of the 32x32 MFMA.
// A-frag: h1[m=lo][k=16*KT+8*hi+j], one swizzled b128 read.
// B-frag: tile[8*hi+j][32*n2+lo], 8 conflict-free b32 reads + bf16 round.
// HF, n2 literals -> acc indices compile-time (rule #20).
#define CONSUME_T(BUF, KT, HF) {                                               \
    const int ao_ = lo * 256 + 32 * (KT) + 16 * hi;                            \
    const short8v a_ = *reinterpret_cast<const short8v*>(                      \
        (const char*)h1b + (ao_ ^ ((lo & 7) << 4)));                           \
    const float* tb_ = &w2t[BUF][hi * 512 + lo];                               \
    _Pragma("unroll")                                                          \
    for (int n2_ = 0; n2_ < 2; ++n2_) {                                        \
        const float* col_ = tb_ + 32 * n2_;                                    \
        short8v bf_;                                                           \
        bf_[0] = bf_rna(col_[0]);   bf_[1] = bf_rna(col_[64]);                 \
        bf_[2] = bf_rna(col_[128]); bf_[3] = bf_rna(col_[192]);                \
        bf_[4] = bf_rna(col_[256]); bf_[5] = bf_rna(col_[320]);                \
        bf_[6] = bf_rna(col_[384]); bf_[7] = bf_rna(col_[448]);                \
        acc[2 * (HF) + n2_] = __builtin_amdgcn_mfma_f32_32x32x16_bf16(         \
            a_, bf_, acc[2 * (HF) + n2_], 0, 0, 0);                            \
    } }

__global__ __launch_bounds__(64, 2) void pixel_mlp_kernel(
    const float* __restrict__ x,    // [BS][DIM_IN]
    const float* __restrict__ W1,   // [P][DIM_IN][H]
    const float* __restrict__ b1,   // [P][H]
    const float* __restrict__ W2,   // [P][H][H]
    const float* __restrict__ b2,   // [P][H]
    const float* __restrict__ W3,   // [P][H]
    const float* __restrict__ b3,   // [P]
    float* __restrict__ y)          // [BS][P]
{
    const int p  = blockIdx.x;
    const int t  = threadIdx.x;     // 0..63, one wave
    const int cc = t & 15;          // layer-1 col group
    const int gg = t >> 4;          // layer-1 row group
    const int c0 = cc << 2;
    const int r0 = gg << 3;
    const int lo = t & 31;          // MFMA row/col lane
    const int hi = t >> 5;          // MFMA k-group

    __shared__ float sxT[DIM_IN][BS];   // 3.2 KB
    __shared__ short h1b[BS][H];        // 8 KB, h1 bf16 bits, XOR-swizzled 16B slots
    __shared__ float w2t[2][16 * 64];   // 8 KB, tile double buffer

    const float* W1p = W1 + (size_t)p * (DIM_IN * H);
    const float* W2p = W2 + (size_t)p * (H * H);

    // ---- small loads first (oldest in vmcnt FIFO; retire before staging) ----
    const float4 b1l = *reinterpret_cast<const float4*>(b1 + (size_t)p * H + c0);
    const float4 b1h = *reinterpret_cast<const float4*>(b1 + (size_t)p * H + 64 + c0);
    float b2v[4], w3v[4];
    #pragma unroll
    for (int nb = 0; nb < 4; ++nb) {
        b2v[nb] = b2[(size_t)p * H + 32 * nb + lo];
        w3v[nb] = W3[(size_t)p * H + 32 * nb + lo];
    }
    const float b3s = b3[p];
    asm volatile("" ::: "memory");

    // tiles (KT=0, HF=0,1) in flight during layer 1
    STAGE_T(0, 0, 0)
    STAGE_T(1, 0, 1)
    asm volatile("" ::: "memory");

    // stage x^T
    for (int i = t; i < DIM_IN * BS; i += 64)
        sxT[i >> 5][i & 31] = x[(i & 31) * DIM_IN + (i >> 5)];
    asm volatile("s_waitcnt lgkmcnt(0)" ::: "memory");

    // ---------------- layer 1: h1 = leaky(x @ W1 + b1), f32 VALU ----------------
    float aL1[8][8];
    {
        const float bv[8] = {b1l.x, b1l.y, b1l.z, b1l.w, b1h.x, b1h.y, b1h.z, b1h.w};
        #pragma unroll
        for (int i = 0; i < 8; ++i)
            #pragma unroll
            for (int c = 0; c < 8; ++c)
                aL1[i][c] = bv[c];
    }
    #pragma unroll 5
    for (int d = 0; d < DIM_IN; ++d) {
        const float4 a0 = *reinterpret_cast<const float4*>(&sxT[d][r0]);
        const float4 a1 = *reinterpret_cast<const float4*>(&sxT[d][r0 + 4]);
        const float av[8] = {a0.x, a0.y, a0.z, a0.w, a1.x, a1.y, a1.z, a1.w};
        const float4 wl = *reinterpret_cast<const float4*>(W1p + d * H + c0);
        const float4 wh = *reinterpret_cast<const float4*>(W1p + d * H + 64 + c0);
        const float wv[8] = {wl.x, wl.y, wl.z, wl.w, wh.x, wh.y, wh.z, wh.w};
        #pragma unroll
        for (int i = 0; i < 8; ++i)
            #pragma unroll
            for (int c = 0; c < 8; ++c)
                aL1[i][c] += av[i] * wv[c];
    }

    // write h1 (leaky, RNE bf16), XOR-swizzled: byte ^= ((row&7)<<4)
    #pragma unroll
    for (int i = 0; i < 8; ++i) {
        short4v lov, hiv;
        lov[0] = bf_rne(leaky(aL1[i][0])); lov[1] = bf_rne(leaky(aL1[i][1]));
        lov[2] = bf_rne(leaky(aL1[i][2])); lov[3] = bf_rne(leaky(aL1[i][3]));
        hiv[0] = bf_rne(leaky(aL1[i][4])); hiv[1] = bf_rne(leaky(aL1[i][5]));
        hiv[2] = bf_rne(leaky(aL1[i][6])); hiv[3] = bf_rne(leaky(aL1[i][7]));
        const int ro = (r0 + i) * 256;
        const int sz = ((r0 + i) & 7) << 4;
        *reinterpret_cast<short4v*>((char*)h1b + ((ro + 8 * cc) ^ sz))       = lov;
        *reinterpret_cast<short4v*>((char*)h1b + ((ro + 128 + 8 * cc) ^ sz)) = hiv;
    }
    asm volatile("s_waitcnt lgkmcnt(0)" ::: "memory");
    __builtin_amdgcn_sched_barrier(0);

    // ---------------- layer 2: h2 = leaky(h1 @ W2 + b2), 32x32x16 MFMA ----------------
    f32x16 acc[4];
    #pragma unroll
    for (int nb = 0; nb < 4; ++nb)
        acc[nb] = (f32x16)(0.f);

    // 16 tiles: KT 0..7 x HF 0,1; buf = HF; 2 tiles (8 insts) in flight;
    // vmcnt(4) = oldest tile fully landed; restage same buf with KT+1.
    #pragma unroll 1
    for (int kt = 0; kt < 7; ++kt) {
        asm volatile("s_waitcnt vmcnt(4)" ::: "memory");
        CONSUME_T(0, kt, 0)
        asm volatile("s_waitcnt lgkmcnt(0)" ::: "memory");
        STAGE_T(0, kt + 1, 0)
        asm volatile("s_waitcnt vmcnt(4)" ::: "memory");
        CONSUME_T(1, kt, 1)
        asm volatile("s_waitcnt lgkmcnt(0)" ::: "memory");
        STAGE_T(1, kt + 1, 1)
    }
    asm volatile("s_waitcnt vmcnt(4)" ::: "memory");
    CONSUME_T(0, 7, 0)
    asm volatile("s_waitcnt vmcnt(0)" ::: "memory");
    CONSUME_T(1, 7, 1)

    // ---------------- layer 3: y = leaky(h2 + b2) @ W3 + b3 ----------------
    // lane (lo,hi) holds D col n = 32*nb + lo, rows r = (reg&3)+8*(reg>>2)+4*hi
    float s[16];
    #pragma unroll
    for (int reg = 0; reg < 16; ++reg) {
        float acc_s = 0.f;
        #pragma unroll
        for (int nb = 0; nb < 4; ++nb)
            acc_s += leaky(acc[nb][reg] + b2v[nb]) * w3v[nb];
        s[reg] = acc_s;
    }
    // reduce across the 32 lo lanes (masks 1..16 stay within the half-wave)
    #pragma unroll
    for (int m = 16; m >= 1; m >>= 1) {
        #pragma unroll
        for (int reg = 0; reg < 16; ++reg)
            s[reg] += __shfl_xor(s[reg], m);
    }
    if (lo == 0) {
        #pragma unroll
        for (int reg = 0; reg < 16; ++reg) {
            const int r = (reg & 3) + 8 * (reg >> 2) + 4 * hi;
            y[(size_t)r * P + p] = s[reg] + b3s;
        }
    }
}

extern "C" void kernel_launch(void* const* d_in, const int* in_sizes, int n_in,
                              void* d_out, int out_size, void* d_ws, size_t ws_size,
                              hipStream_t stream) {
    const float* x  = (const float*)d_in[0];
    const float* W1 = (const float*)d_in[1];
    const float* b1 = (const float*)d_in[2];
    const float* W2 = (const float*)d_in[3];
    const float* b2 = (const float*)d_in[4];
    const float* W3 = (const float*)d_in[5];
    const float* b3 = (const float*)d_in[6];
    float* y = (float*)d_out;

    pixel_mlp_kernel<<<dim3(P), dim3(64), 0, stream>>>(x, W1, b1, W2, b2, W3, b3, y);
}